// Round 1
// baseline (966.376 us; speedup 1.0000x reference)
//
#include <hip/hip_runtime.h>

// Problem constants
#define B 8
#define T 1024
#define C 768
#define H 12
#define D 64
#define M (B * T)   // 8192 rows
#define N C          // 768 cols
#define KDIM C       // 768 inner

// ---------------- GEMM: out[M,N] = A[M,K] @ W[K,N] + bias ----------------
// 64x64 tile, 256 threads (16x16), each thread a 4x4 micro-tile.
// A tile staged transposed (Ast[k][m]) so inner loop uses aligned float4 reads.
constexpr int BM = 64, BN = 64, BK = 16;

__global__ __launch_bounds__(256)
void gemm_bias_kernel(const float* __restrict__ A,
                      const float* __restrict__ W,
                      const float* __restrict__ bias,
                      float* __restrict__ out) {
  __shared__ float Ast[BK][BM + 4];  // pitch 68 floats: rows 16B-aligned
  __shared__ float Bs[BK][BN + 4];
  const int tx = threadIdx.x, ty = threadIdx.y;
  const int tid = ty * 16 + tx;
  const int m0 = blockIdx.y * BM;
  const int n0 = blockIdx.x * BN;

  float acc[4][4] = {};

  for (int k0 = 0; k0 < KDIM; k0 += BK) {
    __syncthreads();  // protect LDS from previous iteration's readers
    // A tile 64x16, transposed into Ast[k][m]
#pragma unroll
    for (int i = 0; i < 4; i++) {
      int e = tid + i * 256;       // 0..1023
      int r = e >> 4, c = e & 15;  // r = m (0..63), c = k (0..15)
      Ast[c][r] = A[(size_t)(m0 + r) * KDIM + k0 + c];
    }
    // B tile 16x64, row-major
#pragma unroll
    for (int i = 0; i < 4; i++) {
      int e = tid + i * 256;
      int r = e >> 6, c = e & 63;  // r = k, c = n
      Bs[r][c] = W[(size_t)(k0 + r) * N + n0 + c];
    }
    __syncthreads();
#pragma unroll
    for (int k = 0; k < BK; k++) {
      float4 a4 = *(const float4*)&Ast[k][ty * 4];
      float4 b4 = *(const float4*)&Bs[k][tx * 4];
      float av[4] = {a4.x, a4.y, a4.z, a4.w};
      float bv[4] = {b4.x, b4.y, b4.z, b4.w};
#pragma unroll
      for (int i = 0; i < 4; i++)
#pragma unroll
        for (int j = 0; j < 4; j++)
          acc[i][j] += av[i] * bv[j];
    }
  }

  float4 bb = *(const float4*)&bias[n0 + tx * 4];
  float bvv[4] = {bb.x, bb.y, bb.z, bb.w};
#pragma unroll
  for (int i = 0; i < 4; i++) {
    int row = m0 + ty * 4 + i;
    float4 o;
    o.x = acc[i][0] + bvv[0];
    o.y = acc[i][1] + bvv[1];
    o.z = acc[i][2] + bvv[2];
    o.w = acc[i][3] + bvv[3];
    *(float4*)&out[(size_t)row * N + n0 + tx * 4] = o;
  }
}

// ---------------- Flash attention (causal), fp32 ----------------
// One block = one (b,h) pair and 64 Q rows. 256 threads (16x16).
// Online softmax; KV tiles of 64 staged in LDS. Fully-masked tiles skipped.
constexpr int BQ = 64, BKV = 64;

__global__ __launch_bounds__(256)
void attn_kernel(const float* __restrict__ Qf,
                 const float* __restrict__ Kf,
                 const float* __restrict__ Vf,
                 float* __restrict__ Of) {
  __shared__ float Qt[D][BQ + 4];   // Q^T tile, scaled
  __shared__ float Kt[D][BKV + 4];  // K^T tile
  __shared__ float Vs[BKV][D + 4];  // V tile row-major
  __shared__ float Pt[BKV][BQ + 4]; // P^T tile

  const int tx = threadIdx.x, ty = threadIdx.y;
  const int tid = ty * 16 + tx;
  const int q0 = blockIdx.x * BQ;
  const int bh = blockIdx.y;
  const int b = bh / H, h = bh % H;
  const float scale = 0.125f;  // 1/sqrt(64)

  float acc[4][4] = {};
  float m_i[4], l_i[4];
#pragma unroll
  for (int i = 0; i < 4; i++) { m_i[i] = -1e30f; l_i[i] = 0.0f; }

  // Stage Q tile transposed, scale folded in
#pragma unroll
  for (int i = 0; i < 4; i++) {
    int e = tid + i * 256;          // float4 index 0..1023
    int r = e >> 4, c4 = e & 15;    // r = q row (0..63), c4 = d/4
    float4 qv = *(const float4*)&Qf[(size_t)(b * T + q0 + r) * C + h * D + c4 * 4];
    Qt[c4 * 4 + 0][r] = qv.x * scale;
    Qt[c4 * 4 + 1][r] = qv.y * scale;
    Qt[c4 * 4 + 2][r] = qv.z * scale;
    Qt[c4 * 4 + 3][r] = qv.w * scale;
  }

  for (int s0 = 0; s0 <= q0; s0 += BKV) {
    __syncthreads();  // previous iteration's LDS readers done (also covers Qt writes)
    // Stage K^T and V tiles
#pragma unroll
    for (int i = 0; i < 4; i++) {
      int e = tid + i * 256;
      int r = e >> 4, c4 = e & 15;
      size_t g = (size_t)(b * T + s0 + r) * C + h * D + c4 * 4;
      float4 kv = *(const float4*)&Kf[g];
      Kt[c4 * 4 + 0][r] = kv.x;
      Kt[c4 * 4 + 1][r] = kv.y;
      Kt[c4 * 4 + 2][r] = kv.z;
      Kt[c4 * 4 + 3][r] = kv.w;
      *(float4*)&Vs[r][c4 * 4] = *(const float4*)&Vf[g];
    }
    __syncthreads();

    // S = (Q*scale) @ K^T  -> each thread 4x4 scores
    float s_acc[4][4] = {};
#pragma unroll 8
    for (int d = 0; d < D; d++) {
      float4 q4 = *(const float4*)&Qt[d][ty * 4];
      float4 k4 = *(const float4*)&Kt[d][tx * 4];
      float qa[4] = {q4.x, q4.y, q4.z, q4.w};
      float ka[4] = {k4.x, k4.y, k4.z, k4.w};
#pragma unroll
      for (int i = 0; i < 4; i++)
#pragma unroll
        for (int j = 0; j < 4; j++)
          s_acc[i][j] += qa[i] * ka[j];
    }

    const bool diag = (s0 == q0);
    float p[4][4];
#pragma unroll
    for (int i = 0; i < 4; i++) {
      int r = ty * 4 + i;  // local q row
      if (diag) {
#pragma unroll
        for (int j = 0; j < 4; j++) {
          int s = tx * 4 + j;
          if (s > r) s_acc[i][j] = -1e30f;
        }
      }
      float mx = fmaxf(fmaxf(s_acc[i][0], s_acc[i][1]),
                       fmaxf(s_acc[i][2], s_acc[i][3]));
#pragma unroll
      for (int off = 1; off < 16; off <<= 1)
        mx = fmaxf(mx, __shfl_xor(mx, off, 64));
      float m_new = fmaxf(m_i[i], mx);
      float rescale = __expf(m_i[i] - m_new);
      m_i[i] = m_new;
      float rs = 0.0f;
#pragma unroll
      for (int j = 0; j < 4; j++) {
        p[i][j] = __expf(s_acc[i][j] - m_new);
        rs += p[i][j];
      }
#pragma unroll
      for (int off = 1; off < 16; off <<= 1)
        rs += __shfl_xor(rs, off, 64);
      l_i[i] = l_i[i] * rescale + rs;
#pragma unroll
      for (int j = 0; j < 4; j++) acc[i][j] *= rescale;
    }

    // Write P transposed: Pt[s][r]
#pragma unroll
    for (int i = 0; i < 4; i++)
#pragma unroll
      for (int j = 0; j < 4; j++)
        Pt[tx * 4 + j][ty * 4 + i] = p[i][j];
    __syncthreads();

    // O += P @ V
#pragma unroll 8
    for (int s = 0; s < BKV; s++) {
      float4 p4 = *(const float4*)&Pt[s][ty * 4];
      float4 v4 = *(const float4*)&Vs[s][tx * 4];
      float pa[4] = {p4.x, p4.y, p4.z, p4.w};
      float va[4] = {v4.x, v4.y, v4.z, v4.w};
#pragma unroll
      for (int i = 0; i < 4; i++)
#pragma unroll
        for (int j = 0; j < 4; j++)
          acc[i][j] += pa[i] * va[j];
    }
  }

  // Epilogue: normalize and store
#pragma unroll
  for (int i = 0; i < 4; i++) {
    int r = q0 + ty * 4 + i;
    float inv = 1.0f / l_i[i];
    float4 o;
    o.x = acc[i][0] * inv;
    o.y = acc[i][1] * inv;
    o.z = acc[i][2] * inv;
    o.w = acc[i][3] * inv;
    *(float4*)&Of[(size_t)(b * T + r) * C + h * D + tx * 4] = o;
  }
}

extern "C" void kernel_launch(void* const* d_in, const int* in_sizes, int n_in,
                              void* d_out, int out_size, void* d_ws, size_t ws_size,
                              hipStream_t stream) {
  const float* x  = (const float*)d_in[0];
  // d_in[1] = mask (causal tril) — applied analytically, not read
  const float* Wq = (const float*)d_in[2];
  const float* bq = (const float*)d_in[3];
  const float* Wk = (const float*)d_in[4];
  const float* bk = (const float*)d_in[5];
  const float* Wv = (const float*)d_in[6];
  const float* bv = (const float*)d_in[7];
  const float* Wo = (const float*)d_in[8];
  const float* bo = (const float*)d_in[9];
  float* out = (float*)d_out;

  const size_t MC = (size_t)M * C;  // 6,291,456 floats
  float* ws = (float*)d_ws;
  float* Q  = ws;
  float* Kk = ws + MC;
  float* Vv = ws + 2 * MC;
  float* Oa = ws + 3 * MC;

  dim3 blk(16, 16);
  dim3 gemm_grid(N / BN, M / BM);   // (12, 128)
  dim3 attn_grid(T / BQ, B * H);    // (16, 96)

  gemm_bias_kernel<<<gemm_grid, blk, 0, stream>>>(x, Wq, bq, Q);
  gemm_bias_kernel<<<gemm_grid, blk, 0, stream>>>(x, Wk, bk, Kk);
  gemm_bias_kernel<<<gemm_grid, blk, 0, stream>>>(x, Wv, bv, Vv);
  attn_kernel<<<attn_grid, blk, 0, stream>>>(Q, Kk, Vv, Oa);
  gemm_bias_kernel<<<gemm_grid, blk, 0, stream>>>(Oa, Wo, bo, out);
}

// Round 2
// 177.942 us; speedup vs baseline: 5.4308x; 5.4308x over previous
//
#include <hip/hip_runtime.h>

#define B 8
#define T 1024
#define C 768
#define H 12
#define D 64
#define M (B * T)     // 8192

typedef unsigned short u16;
typedef unsigned int u32;
typedef __attribute__((ext_vector_type(8))) short bf16x8;
typedef __attribute__((ext_vector_type(4))) float f32x4;

__device__ __forceinline__ u16 f2bf(float f) {
  union { float f; u32 u; } c; c.f = f;
  u32 r = c.u + 0x7FFF + ((c.u >> 16) & 1);
  return (u16)(r >> 16);
}

__device__ __forceinline__ void gload16(const void* g, void* l) {
  __builtin_amdgcn_global_load_lds(
      (const __attribute__((address_space(1))) void*)g,
      (__attribute__((address_space(3))) void*)l, 16, 0, 0);
}

// swizzle for 64B LDS rows (4x16B slots): conflict-free fragment reads
__device__ __forceinline__ int swzA(int row) {
  return (row & 3) ^ ((row >> 2) & 1);
}

// ---------------- fp32 -> bf16 convert (x) ----------------
__global__ __launch_bounds__(256) void xconv_kernel(const float* __restrict__ in,
                                                    u16* __restrict__ out, int n4) {
  int i = blockIdx.x * 256 + threadIdx.x;
  int stride = gridDim.x * 256;
  for (; i < n4; i += stride) {
    float4 v = ((const float4*)in)[i];
    ushort4 o;
    o.x = f2bf(v.x); o.y = f2bf(v.y); o.z = f2bf(v.z); o.w = f2bf(v.w);
    ((ushort4*)out)[i] = o;
  }
}

// ---------------- weight transpose+convert: Wt[n][k] = bf16(W[k][n]) ----------------
__global__ __launch_bounds__(256) void wtrans_kernel(const float* __restrict__ Wq,
                                                     const float* __restrict__ Wk,
                                                     const float* __restrict__ Wv,
                                                     const float* __restrict__ Wo,
                                                     u16* __restrict__ WtQKV,
                                                     u16* __restrict__ WoT) {
  __shared__ float t[32][33];
  const int z = blockIdx.z;
  const float* W = (z == 0) ? Wq : (z == 1) ? Wk : (z == 2) ? Wv : Wo;
  u16* dst = (z < 3) ? (WtQKV + (size_t)z * 768 * 768) : WoT;
  const int k0 = blockIdx.y * 32, n0 = blockIdx.x * 32;
  const int tx = threadIdx.x & 31, ty = threadIdx.x >> 5;  // ty 0..7
#pragma unroll
  for (int i = 0; i < 4; i++) {
    int r = ty * 4 + i;
    t[r][tx] = W[(size_t)(k0 + r) * 768 + n0 + tx];
  }
  __syncthreads();
#pragma unroll
  for (int i = 0; i < 4; i++) {
    int r = ty * 4 + i;
    dst[(size_t)(n0 + r) * 768 + k0 + tx] = f2bf(t[tx][r]);
  }
}

// ---------------- bf16 MFMA GEMM: out[M][768(seg)] = A[M][768] @ Wt^T + bias ----------------
// 128x128 tile, BK=32, 4 waves (2x2), each wave 64x64 = 4x4 fragments of 16x16x32.
template <typename OutT>
__global__ __launch_bounds__(256) void gemm_mfma_kernel(
    const u16* __restrict__ A,    // [M][768] bf16
    const u16* __restrict__ Wt,   // [NTOT][768] bf16 (= W^T)
    const float* __restrict__ b0, const float* __restrict__ b1, const float* __restrict__ b2,
    OutT* __restrict__ o0, OutT* __restrict__ o1, OutT* __restrict__ o2) {
  __shared__ u16 As[128 * 32];
  __shared__ u16 Bs[128 * 32];
  const int tid = threadIdx.x;
  const int w = tid >> 6, l = tid & 63;
  const int g = l >> 4, c = l & 15;
  const int m0 = blockIdx.y * 128;
  const int n0g = blockIdx.x * 128;       // global col (within NTOT)
  const int seg = n0g / 768;
  const int n0 = n0g - seg * 768;
  const float* bias = (seg == 0) ? b0 : (seg == 1) ? b1 : b2;
  OutT* out = (seg == 0) ? o0 : (seg == 1) ? o1 : o2;
  const int wr = (w >> 1) * 64, wc = (w & 1) * 64;

  f32x4 acc[4][4];
#pragma unroll
  for (int i = 0; i < 4; i++)
#pragma unroll
    for (int j = 0; j < 4; j++) acc[i][j] = f32x4{0.f, 0.f, 0.f, 0.f};

  for (int k0 = 0; k0 < 768; k0 += 32) {
    __syncthreads();
    // stage A and B tiles: swizzled global source, linear LDS dest
#pragma unroll
    for (int t = 0; t < 2; t++) {
      int ii = w * 2 + t;
      int e16 = ii * 64 + l;
      int row = e16 >> 2, slot = e16 & 3;
      int gs = slot ^ swzA(row);
      gload16(A + (size_t)(m0 + row) * 768 + k0 + gs * 8, (char*)As + ii * 1024);
    }
#pragma unroll
    for (int t = 0; t < 2; t++) {
      int ii = w * 2 + t;
      int e16 = ii * 64 + l;
      int row = e16 >> 2, slot = e16 & 3;
      int gs = slot ^ swzA(row);
      gload16(Wt + (size_t)(n0g + row) * 768 + k0 + gs * 8, (char*)Bs + ii * 1024);
    }
    __syncthreads();

    bf16x8 af[4], bfr[4];
#pragma unroll
    for (int i = 0; i < 4; i++) {
      int row = wr + i * 16 + c;
      int slot = g ^ swzA(row);
      af[i] = *(const bf16x8*)(As + row * 32 + slot * 8);
    }
#pragma unroll
    for (int j = 0; j < 4; j++) {
      int row = wc + j * 16 + c;
      int slot = g ^ swzA(row);
      bfr[j] = *(const bf16x8*)(Bs + row * 32 + slot * 8);
    }
#pragma unroll
    for (int i = 0; i < 4; i++)
#pragma unroll
      for (int j = 0; j < 4; j++)
        acc[i][j] = __builtin_amdgcn_mfma_f32_16x16x32_bf16(af[i], bfr[j], acc[i][j], 0, 0, 0);
  }

  // epilogue: bias add, store (C layout: col = lane&15, row = (lane>>4)*4 + reg)
#pragma unroll
  for (int j = 0; j < 4; j++) {
    int col = n0 + wc + j * 16 + c;
    float bb = bias[col];
#pragma unroll
    for (int i = 0; i < 4; i++) {
#pragma unroll
      for (int r = 0; r < 4; r++) {
        int row = m0 + wr + i * 16 + g * 4 + r;
        float v = acc[i][j][r] + bb;
        if constexpr (sizeof(OutT) == 2) {
          ((u16*)out)[(size_t)row * 768 + col] = f2bf(v);
        } else {
          ((float*)out)[(size_t)row * 768 + col] = v;
        }
      }
    }
  }
}

// ---------------- bf16 MFMA flash attention (causal) ----------------
// Block: one (b,h), 64 Q rows; 4 waves x 16 rows. KV tiles of 64.
__global__ __launch_bounds__(256) void attn_mfma_kernel(
    const u16* __restrict__ Qb, const u16* __restrict__ Kb,
    const u16* __restrict__ Vb, u16* __restrict__ Ob) {
  __shared__ u16 Ks[64 * 64];      // [kv][d], source-swizzled (slot ^= row&7)
  __shared__ u16 Vt[64][72];       // [d][kv], padded
  __shared__ u16 Ps[4][16][72];    // per-wave P [qrow][kv], padded

  const int tid = threadIdx.x;
  const int w = tid >> 6, l = tid & 63;
  const int g = l >> 4, c = l & 15;
  const int q0 = blockIdx.x * 64;
  const int bh = blockIdx.y;
  const int b = bh / H, h = bh % H;
  const int qw = q0 + w * 16;

  // preload Q fragments: A-frag lane row = l&15, k(d) = kc*32 + g*8 ..+7
  bf16x8 qf[2];
  {
    size_t base = (size_t)(b * T + qw + c) * C + h * D;
    qf[0] = *(const bf16x8*)(Qb + base + g * 8);
    qf[1] = *(const bf16x8*)(Qb + base + 32 + g * 8);
  }

  f32x4 acc[4];
#pragma unroll
  for (int j = 0; j < 4; j++) acc[j] = f32x4{0.f, 0.f, 0.f, 0.f};
  float m_i[4], l_i[4];
#pragma unroll
  for (int r = 0; r < 4; r++) { m_i[r] = -1e30f; l_i[r] = 0.f; }

  const int nt = q0 / 64 + 1;
  for (int it = 0; it < nt; it++) {
    const int s0 = it * 64;
    __syncthreads();
    // stage K via global_load_lds, source pre-swizzled (8x16B slots per 128B row)
#pragma unroll
    for (int t = 0; t < 2; t++) {
      int ii = w * 2 + t;
      int e16 = ii * 64 + l;
      int row = e16 >> 3, slot = e16 & 7;
      int gs = slot ^ (row & 7);
      gload16(Kb + (size_t)(b * T + s0 + row) * C + h * D + gs * 8, (char*)Ks + ii * 1024);
    }
    // stage V transposed (reg-staged scatter)
#pragma unroll
    for (int rep = 0; rep < 4; rep++) {
      int kv = tid & 63;
      int d0 = (tid >> 6) * 16 + rep * 4;
      ushort4 v4 = *(const ushort4*)(Vb + (size_t)(b * T + s0 + kv) * C + h * D + d0);
      Vt[d0 + 0][kv] = v4.x;
      Vt[d0 + 1][kv] = v4.y;
      Vt[d0 + 2][kv] = v4.z;
      Vt[d0 + 3][kv] = v4.w;
    }
    __syncthreads();

    const bool active = (s0 <= qw + 15);
    if (active) {
      // S = Q @ K^T : 4 kv-fragments of 16
      f32x4 s[4];
#pragma unroll
      for (int f = 0; f < 4; f++) s[f] = f32x4{0.f, 0.f, 0.f, 0.f};
#pragma unroll
      for (int f = 0; f < 4; f++) {
#pragma unroll
        for (int kc = 0; kc < 2; kc++) {
          int kvrow = f * 16 + c;
          int slot = (kc * 4 + g) ^ (kvrow & 7);
          bf16x8 kf = *(const bf16x8*)(Ks + kvrow * 64 + slot * 8);
          s[f] = __builtin_amdgcn_mfma_f32_16x16x32_bf16(qf[kc], kf, s[f], 0, 0, 0);
        }
      }
      // scale + causal mask + per-lane partial max
      const float scale = 0.125f;
      float mx[4], resc[4], rs[4];
#pragma unroll
      for (int r = 0; r < 4; r++) {
        int q = qw + g * 4 + r;
        float mr = -1e30f;
#pragma unroll
        for (int f = 0; f < 4; f++) {
          int kv = s0 + f * 16 + c;
          float v = s[f][r] * scale;
          v = (kv <= q) ? v : -1e30f;
          s[f][r] = v;
          mr = fmaxf(mr, v);
        }
        mx[r] = mr;
      }
#pragma unroll
      for (int off = 1; off < 16; off <<= 1)
#pragma unroll
        for (int r = 0; r < 4; r++) mx[r] = fmaxf(mx[r], __shfl_xor(mx[r], off, 64));
#pragma unroll
      for (int r = 0; r < 4; r++) {
        float m_new = fmaxf(m_i[r], mx[r]);
        resc[r] = __expf(m_i[r] - m_new);
        m_i[r] = m_new;
        float sum = 0.f;
#pragma unroll
        for (int f = 0; f < 4; f++) {
          float p = __expf(s[f][r] - m_new);
          s[f][r] = p;
          sum += p;
        }
        rs[r] = sum;
      }
#pragma unroll
      for (int off = 1; off < 16; off <<= 1)
#pragma unroll
        for (int r = 0; r < 4; r++) rs[r] += __shfl_xor(rs[r], off, 64);
#pragma unroll
      for (int r = 0; r < 4; r++) {
        l_i[r] = l_i[r] * resc[r] + rs[r];
#pragma unroll
        for (int j = 0; j < 4; j++) acc[j][r] *= resc[r];
      }
      // write P (bf16) to per-wave LDS
#pragma unroll
      for (int f = 0; f < 4; f++)
#pragma unroll
        for (int r = 0; r < 4; r++)
          Ps[w][g * 4 + r][f * 16 + c] = f2bf(s[f][r]);
      // O += P @ V
#pragma unroll
      for (int kc = 0; kc < 2; kc++) {
        bf16x8 pf = *(const bf16x8*)(&Ps[w][c][kc * 32 + g * 8]);
#pragma unroll
        for (int j = 0; j < 4; j++) {
          bf16x8 vf = *(const bf16x8*)(&Vt[j * 16 + c][kc * 32 + g * 8]);
          acc[j] = __builtin_amdgcn_mfma_f32_16x16x32_bf16(pf, vf, acc[j], 0, 0, 0);
        }
      }
    }
  }

  // epilogue: normalize, store bf16
  float inv[4];
#pragma unroll
  for (int r = 0; r < 4; r++) inv[r] = 1.f / l_i[r];
#pragma unroll
  for (int j = 0; j < 4; j++) {
#pragma unroll
    for (int r = 0; r < 4; r++) {
      int row = qw + g * 4 + r;
      int col = j * 16 + c;
      Ob[(size_t)(b * T + row) * C + h * D + col] = f2bf(acc[j][r] * inv[r]);
    }
  }
}

extern "C" void kernel_launch(void* const* d_in, const int* in_sizes, int n_in,
                              void* d_out, int out_size, void* d_ws, size_t ws_size,
                              hipStream_t stream) {
  const float* x  = (const float*)d_in[0];
  const float* Wq = (const float*)d_in[2];
  const float* bq = (const float*)d_in[3];
  const float* Wk = (const float*)d_in[4];
  const float* bk = (const float*)d_in[5];
  const float* Wv = (const float*)d_in[6];
  const float* bv = (const float*)d_in[7];
  const float* Wo = (const float*)d_in[8];
  const float* bo = (const float*)d_in[9];
  float* out = (float*)d_out;

  const size_t MC2 = (size_t)M * C * 2;  // bf16 activation bytes = 12.58 MB
  char* ws = (char*)d_ws;
  u16* xb    = (u16*)(ws);
  u16* WtQKV = (u16*)(ws + MC2);
  u16* WoT   = (u16*)(ws + MC2 + 3538944);
  u16* Qb    = (u16*)(ws + MC2 + 3538944 + 1179648);
  u16* Kb    = (u16*)((char*)Qb + MC2);
  u16* Vb    = (u16*)((char*)Kb + MC2);
  u16* Ob    = (u16*)((char*)Vb + MC2);

  xconv_kernel<<<2048, 256, 0, stream>>>(x, xb, M * C / 4);
  wtrans_kernel<<<dim3(24, 24, 4), 256, 0, stream>>>(Wq, Wk, Wv, Wo, WtQKV, WoT);
  // fused QKV GEMM: NTOT = 2304
  gemm_mfma_kernel<u16><<<dim3(18, 64), 256, 0, stream>>>(
      xb, WtQKV, bq, bk, bv, Qb, Kb, Vb);
  attn_mfma_kernel<<<dim3(16, 96), 256, 0, stream>>>(Qb, Kb, Vb, Ob);
  gemm_mfma_kernel<float><<<dim3(6, 64), 256, 0, stream>>>(
      Ob, WoT, bo, bo, bo, out, out, out);
}

// Round 3
// 144.716 us; speedup vs baseline: 6.6778x; 1.2296x over previous
//
#include <hip/hip_runtime.h>

#define B 8
#define T 1024
#define C 768
#define H 12
#define D 64
#define M (B * T)     // 8192

typedef unsigned short u16;
typedef unsigned int u32;
typedef __attribute__((ext_vector_type(8))) short bf16x8;
typedef __attribute__((ext_vector_type(4))) float f32x4;

__device__ __forceinline__ u16 f2bf(float f) {
  union { float f; u32 u; } c; c.f = f;
  u32 r = c.u + 0x7FFF + ((c.u >> 16) & 1);
  return (u16)(r >> 16);
}

__device__ __forceinline__ void gload16(const void* g, void* l) {
  __builtin_amdgcn_global_load_lds(
      (const __attribute__((address_space(1))) void*)g,
      (__attribute__((address_space(3))) void*)l, 16, 0, 0);
}

// swizzle for 64B LDS rows (4x16B slots): conflict-free fragment reads
__device__ __forceinline__ int swzA(int row) {
  return (row & 3) ^ ((row >> 2) & 1);
}

// ---------------- fp32 -> bf16 convert (x) ----------------
__global__ __launch_bounds__(256) void xconv_kernel(const float* __restrict__ in,
                                                    u16* __restrict__ out, int n4) {
  int i = blockIdx.x * 256 + threadIdx.x;
  int stride = gridDim.x * 256;
  for (; i < n4; i += stride) {
    float4 v = ((const float4*)in)[i];
    ushort4 o;
    o.x = f2bf(v.x); o.y = f2bf(v.y); o.z = f2bf(v.z); o.w = f2bf(v.w);
    ((ushort4*)out)[i] = o;
  }
}

// ---------------- weight transpose+convert: Wt[n][k] = bf16(W[k][n]) ----------------
__global__ __launch_bounds__(256) void wtrans_kernel(const float* __restrict__ Wq,
                                                     const float* __restrict__ Wk,
                                                     const float* __restrict__ Wv,
                                                     const float* __restrict__ Wo,
                                                     u16* __restrict__ WtQKV,
                                                     u16* __restrict__ WoT) {
  __shared__ float t[32][33];
  const int z = blockIdx.z;
  const float* W = (z == 0) ? Wq : (z == 1) ? Wk : (z == 2) ? Wv : Wo;
  u16* dst = (z < 3) ? (WtQKV + (size_t)z * 768 * 768) : WoT;
  const int k0 = blockIdx.y * 32, n0 = blockIdx.x * 32;
  const int tx = threadIdx.x & 31, ty = threadIdx.x >> 5;  // ty 0..7
#pragma unroll
  for (int i = 0; i < 4; i++) {
    int r = ty * 4 + i;
    t[r][tx] = W[(size_t)(k0 + r) * 768 + n0 + tx];
  }
  __syncthreads();
#pragma unroll
  for (int i = 0; i < 4; i++) {
    int r = ty * 4 + i;
    dst[(size_t)(n0 + r) * 768 + k0 + tx] = f2bf(t[tx][r]);
  }
}

// ---------------- bf16 MFMA GEMM: out[M][768(seg)] = (A[M][768] @ Wt^T + bias) * sc ----------
// 128x128 tile, BK=32, 4 waves (2x2), each wave 64x64 = 4x4 fragments of 16x16x32.
template <typename OutT>
__global__ __launch_bounds__(256) void gemm_mfma_kernel(
    const u16* __restrict__ A,    // [M][768] bf16
    const u16* __restrict__ Wt,   // [NTOT][768] bf16 (= W^T)
    const float* __restrict__ b0, const float* __restrict__ b1, const float* __restrict__ b2,
    OutT* __restrict__ o0, OutT* __restrict__ o1, OutT* __restrict__ o2,
    float sc0, float sc1, float sc2) {
  __shared__ u16 As[128 * 32];
  __shared__ u16 Bs[128 * 32];
  const int tid = threadIdx.x;
  const int w = tid >> 6, l = tid & 63;
  const int g = l >> 4, c = l & 15;
  const int m0 = blockIdx.y * 128;
  const int n0g = blockIdx.x * 128;       // global col (within NTOT)
  const int seg = n0g / 768;
  const int n0 = n0g - seg * 768;
  const float* bias = (seg == 0) ? b0 : (seg == 1) ? b1 : b2;
  OutT* out = (seg == 0) ? o0 : (seg == 1) ? o1 : o2;
  const float sc = (seg == 0) ? sc0 : (seg == 1) ? sc1 : sc2;
  const int wr = (w >> 1) * 64, wc = (w & 1) * 64;

  f32x4 acc[4][4];
#pragma unroll
  for (int i = 0; i < 4; i++)
#pragma unroll
    for (int j = 0; j < 4; j++) acc[i][j] = f32x4{0.f, 0.f, 0.f, 0.f};

  for (int k0 = 0; k0 < 768; k0 += 32) {
    __syncthreads();
#pragma unroll
    for (int t = 0; t < 2; t++) {
      int ii = w * 2 + t;
      int e16 = ii * 64 + l;
      int row = e16 >> 2, slot = e16 & 3;
      int gs = slot ^ swzA(row);
      gload16(A + (size_t)(m0 + row) * 768 + k0 + gs * 8, (char*)As + ii * 1024);
    }
#pragma unroll
    for (int t = 0; t < 2; t++) {
      int ii = w * 2 + t;
      int e16 = ii * 64 + l;
      int row = e16 >> 2, slot = e16 & 3;
      int gs = slot ^ swzA(row);
      gload16(Wt + (size_t)(n0g + row) * 768 + k0 + gs * 8, (char*)Bs + ii * 1024);
    }
    __syncthreads();

    bf16x8 af[4], bfr[4];
#pragma unroll
    for (int i = 0; i < 4; i++) {
      int row = wr + i * 16 + c;
      int slot = g ^ swzA(row);
      af[i] = *(const bf16x8*)(As + row * 32 + slot * 8);
    }
#pragma unroll
    for (int j = 0; j < 4; j++) {
      int row = wc + j * 16 + c;
      int slot = g ^ swzA(row);
      bfr[j] = *(const bf16x8*)(Bs + row * 32 + slot * 8);
    }
#pragma unroll
    for (int i = 0; i < 4; i++)
#pragma unroll
      for (int j = 0; j < 4; j++)
        acc[i][j] = __builtin_amdgcn_mfma_f32_16x16x32_bf16(af[i], bfr[j], acc[i][j], 0, 0, 0);
  }

  // epilogue (C layout: col = lane&15, row = (lane>>4)*4 + reg)
#pragma unroll
  for (int j = 0; j < 4; j++) {
    int col = n0 + wc + j * 16 + c;
    float bb = bias[col];
#pragma unroll
    for (int i = 0; i < 4; i++) {
#pragma unroll
      for (int r = 0; r < 4; r++) {
        int row = m0 + wr + i * 16 + g * 4 + r;
        float v = (acc[i][j][r] + bb) * sc;
        if constexpr (sizeof(OutT) == 2) {
          ((u16*)out)[(size_t)row * 768 + col] = f2bf(v);
        } else {
          ((float*)out)[(size_t)row * 768 + col] = v;
        }
      }
    }
  }
}

// ---------------- bf16 MFMA flash attention (causal), exp2 domain ----------------
// Block: one (b,h), 64 Q rows; 4 waves x 16 rows. KV tiles of 128.
// Q is pre-scaled by (1/sqrt(D))*log2(e) in the QKV GEMM epilogue.
__global__ __launch_bounds__(256) void attn_mfma_kernel(
    const u16* __restrict__ Qb, const u16* __restrict__ Kb,
    const u16* __restrict__ Vb, u16* __restrict__ Ob) {
  __shared__ u16 Ks[128 * 64];     // [kv][d], source-swizzled (slot ^= row&7)
  __shared__ u16 Vt[64][136];      // [d][kv], padded
  __shared__ u16 Ps[4][16][136];   // per-wave P [qrow][kv], padded

  const int tid = threadIdx.x;
  const int w = tid >> 6, l = tid & 63;
  const int g = l >> 4, c = l & 15;

  // XCD-chunked, work-descending launch order (1536 blocks, 192 per XCD)
  const int wg = blockIdx.x;
  const int logical = (wg & 7) * 192 + (wg >> 3);
  const int bh = logical >> 4;
  const int qi = 15 - (logical & 15);
  const int q0 = qi * 64;
  const int b = bh / H, h = bh % H;
  const int qw = q0 + w * 16;

  bf16x8 qf[2];
  {
    size_t base = (size_t)(b * T + qw + c) * C + h * D;
    qf[0] = *(const bf16x8*)(Qb + base + g * 8);
    qf[1] = *(const bf16x8*)(Qb + base + 32 + g * 8);
  }

  f32x4 acc[4];
#pragma unroll
  for (int j = 0; j < 4; j++) acc[j] = f32x4{0.f, 0.f, 0.f, 0.f};
  float m_i[4], l_p[4];  // running max (log2 domain), per-lane partial l
#pragma unroll
  for (int r = 0; r < 4; r++) { m_i[r] = -1e30f; l_p[r] = 0.f; }

  const int nt = q0 / 128 + 1;
  for (int it = 0; it < nt; it++) {
    const int s0 = it * 128;
    __syncthreads();
    // stage K via global_load_lds: 1024 16B-chunks, source pre-swizzled
#pragma unroll
    for (int t = 0; t < 4; t++) {
      int ii = w * 4 + t;
      int e16 = ii * 64 + l;
      int row = e16 >> 3, slot = e16 & 7;
      int gs = slot ^ (row & 7);
      gload16(Kb + (size_t)(b * T + s0 + row) * C + h * D + gs * 8, (char*)Ks + ii * 1024);
    }
    // stage V transposed (reg-staged scatter)
    {
      int kv = tid & 127;
      int dh = tid >> 7;  // 0..1
      size_t vb = (size_t)(b * T + s0 + kv) * C + h * D + dh * 32;
#pragma unroll
      for (int rep = 0; rep < 4; rep++) {
        bf16x8 v8 = *(const bf16x8*)(Vb + vb + rep * 8);
        int d0 = dh * 32 + rep * 8;
#pragma unroll
        for (int e = 0; e < 8; e++) Vt[d0 + e][kv] = (u16)v8[e];
      }
    }
    __syncthreads();

    const bool active = (s0 <= qw + 15);
    if (active) {
      // S = Q' @ K^T : 8 kv-fragments of 16
      f32x4 s[8];
#pragma unroll
      for (int f = 0; f < 8; f++) s[f] = f32x4{0.f, 0.f, 0.f, 0.f};
#pragma unroll
      for (int f = 0; f < 8; f++) {
        int kvrow = f * 16 + c;
#pragma unroll
        for (int kc = 0; kc < 2; kc++) {
          int slot = (kc * 4 + g) ^ (kvrow & 7);
          bf16x8 kf = *(const bf16x8*)(Ks + kvrow * 64 + slot * 8);
          s[f] = __builtin_amdgcn_mfma_f32_16x16x32_bf16(qf[kc], kf, s[f], 0, 0, 0);
        }
      }
      // causal mask only on partial tiles (wave-uniform)
      const bool partial = (s0 + 127 > qw);
      if (partial) {
#pragma unroll
        for (int r = 0; r < 4; r++) {
          int q = qw + g * 4 + r;
#pragma unroll
          for (int f = 0; f < 8; f++) {
            int kv = s0 + f * 16 + c;
            if (kv > q) s[f][r] = -1e30f;
          }
        }
      }
      // per-row max (log2 domain)
      float mx[4];
#pragma unroll
      for (int r = 0; r < 4; r++) {
        float mr = s[0][r];
#pragma unroll
        for (int f = 1; f < 8; f++) mr = fmaxf(mr, s[f][r]);
        mx[r] = mr;
      }
#pragma unroll
      for (int off = 1; off < 16; off <<= 1)
#pragma unroll
        for (int r = 0; r < 4; r++) mx[r] = fmaxf(mx[r], __shfl_xor(mx[r], off, 64));
      // defer-max: skip rescale when max grew by <= 8 (P bounded by 2^8)
      bool defer = true;
#pragma unroll
      for (int r = 0; r < 4; r++) defer = defer && (mx[r] <= m_i[r] + 8.0f);
      if (!__all(defer)) {
#pragma unroll
        for (int r = 0; r < 4; r++) {
          float mn = fmaxf(m_i[r], mx[r]);
          float rc = exp2f(m_i[r] - mn);
          m_i[r] = mn;
          l_p[r] *= rc;
#pragma unroll
          for (int j = 0; j < 4; j++) acc[j][r] *= rc;
        }
      }
      // P = exp2(S - m), per-lane partial row sum (reduced in epilogue)
#pragma unroll
      for (int r = 0; r < 4; r++) {
        float sum = 0.f;
#pragma unroll
        for (int f = 0; f < 8; f++) {
          float p = exp2f(s[f][r] - m_i[r]);
          s[f][r] = p;
          sum += p;
        }
        l_p[r] += sum;
      }
      // write P (bf16) to per-wave LDS
#pragma unroll
      for (int f = 0; f < 8; f++)
#pragma unroll
        for (int r = 0; r < 4; r++)
          Ps[w][g * 4 + r][f * 16 + c] = f2bf(s[f][r]);
      // O += P @ V
#pragma unroll
      for (int kc = 0; kc < 4; kc++) {
        bf16x8 pf = *(const bf16x8*)(&Ps[w][c][kc * 32 + g * 8]);
#pragma unroll
        for (int j = 0; j < 4; j++) {
          bf16x8 vf = *(const bf16x8*)(&Vt[j * 16 + c][kc * 32 + g * 8]);
          acc[j] = __builtin_amdgcn_mfma_f32_16x16x32_bf16(pf, vf, acc[j], 0, 0, 0);
        }
      }
    }
  }

  // epilogue: reduce l across the 16-lane group, normalize, store bf16
  float inv[4];
#pragma unroll
  for (int r = 0; r < 4; r++) {
    float v = l_p[r];
#pragma unroll
    for (int off = 1; off < 16; off <<= 1) v += __shfl_xor(v, off, 64);
    inv[r] = 1.f / v;
  }
#pragma unroll
  for (int j = 0; j < 4; j++) {
#pragma unroll
    for (int r = 0; r < 4; r++) {
      int row = qw + g * 4 + r;
      int col = j * 16 + c;
      Ob[(size_t)(b * T + row) * C + h * D + col] = f2bf(acc[j][r] * inv[r]);
    }
  }
}

extern "C" void kernel_launch(void* const* d_in, const int* in_sizes, int n_in,
                              void* d_out, int out_size, void* d_ws, size_t ws_size,
                              hipStream_t stream) {
  const float* x  = (const float*)d_in[0];
  const float* Wq = (const float*)d_in[2];
  const float* bq = (const float*)d_in[3];
  const float* Wk = (const float*)d_in[4];
  const float* bk = (const float*)d_in[5];
  const float* Wv = (const float*)d_in[6];
  const float* bv = (const float*)d_in[7];
  const float* Wo = (const float*)d_in[8];
  const float* bo = (const float*)d_in[9];
  float* out = (float*)d_out;

  const size_t MC2 = (size_t)M * C * 2;  // bf16 activation bytes = 12.58 MB
  char* ws = (char*)d_ws;
  u16* xb    = (u16*)(ws);
  u16* WtQKV = (u16*)(ws + MC2);
  u16* WoT   = (u16*)(ws + MC2 + 3538944);
  u16* Qb    = (u16*)(ws + MC2 + 3538944 + 1179648);
  u16* Kb    = (u16*)((char*)Qb + MC2);
  u16* Vb    = (u16*)((char*)Kb + MC2);
  u16* Ob    = (u16*)((char*)Vb + MC2);

  // Q pre-scale: (1/sqrt(D)) * log2(e) -> softmax in exp2 domain
  const float qscale = 0.125f * 1.4426950408889634f;

  xconv_kernel<<<2048, 256, 0, stream>>>(x, xb, M * C / 4);
  wtrans_kernel<<<dim3(24, 24, 4), 256, 0, stream>>>(Wq, Wk, Wv, Wo, WtQKV, WoT);
  gemm_mfma_kernel<u16><<<dim3(18, 64), 256, 0, stream>>>(
      xb, WtQKV, bq, bk, bv, Qb, Kb, Vb, qscale, 1.f, 1.f);
  attn_mfma_kernel<<<1536, 256, 0, stream>>>(Qb, Kb, Vb, Ob);
  gemm_mfma_kernel<float><<<dim3(6, 64), 256, 0, stream>>>(
      Ob, WoT, bo, bo, bo, out, out, out, 1.f, 1.f, 1.f);
}

// Round 4
// 139.251 us; speedup vs baseline: 6.9398x; 1.0392x over previous
//
#include <hip/hip_runtime.h>
#include <hip/hip_bf16.h>

#define B 8
#define T 1024
#define C 768
#define H 12
#define D 64
#define M (B * T)     // 8192

typedef unsigned short u16;
typedef unsigned int u32;
typedef __attribute__((ext_vector_type(8))) short bf16x8;
typedef __attribute__((ext_vector_type(4))) float f32x4;

__device__ __forceinline__ u16 f2bf(float f) {
  union { float f; u32 u; } c; c.f = f;
  u32 r = c.u + 0x7FFF + ((c.u >> 16) & 1);
  return (u16)(r >> 16);
}

__device__ __forceinline__ void gload16(const void* g, void* l) {
  __builtin_amdgcn_global_load_lds(
      (const __attribute__((address_space(1))) void*)g,
      (__attribute__((address_space(3))) void*)l, 16, 0, 0);
}

// swizzle for 64B LDS rows (4x16B slots): conflict-free fragment reads
__device__ __forceinline__ int swzA(int row) {
  return (row & 3) ^ ((row >> 2) & 1);
}

// ---------------- fp32 -> bf16 convert (x) ----------------
__global__ __launch_bounds__(256) void xconv_kernel(const float* __restrict__ in,
                                                    u16* __restrict__ out, int n4) {
  int i = blockIdx.x * 256 + threadIdx.x;
  int stride = gridDim.x * 256;
  for (; i < n4; i += stride) {
    float4 v = ((const float4*)in)[i];
    ushort4 o;
    o.x = f2bf(v.x); o.y = f2bf(v.y); o.z = f2bf(v.z); o.w = f2bf(v.w);
    ((ushort4*)out)[i] = o;
  }
}

// ---------------- weight transpose+convert: Wt[n][k] = bf16(W[k][n]) ----------------
__global__ __launch_bounds__(256) void wtrans_kernel(const float* __restrict__ Wq,
                                                     const float* __restrict__ Wk,
                                                     const float* __restrict__ Wv,
                                                     const float* __restrict__ Wo,
                                                     u16* __restrict__ WtQKV,
                                                     u16* __restrict__ WoT) {
  __shared__ float t[32][33];
  const int z = blockIdx.z;
  const float* W = (z == 0) ? Wq : (z == 1) ? Wk : (z == 2) ? Wv : Wo;
  u16* dst = (z < 3) ? (WtQKV + (size_t)z * 768 * 768) : WoT;
  const int k0 = blockIdx.y * 32, n0 = blockIdx.x * 32;
  const int tx = threadIdx.x & 31, ty = threadIdx.x >> 5;  // ty 0..7
#pragma unroll
  for (int i = 0; i < 4; i++) {
    int r = ty * 4 + i;
    t[r][tx] = W[(size_t)(k0 + r) * 768 + n0 + tx];
  }
  __syncthreads();
#pragma unroll
  for (int i = 0; i < 4; i++) {
    int r = ty * 4 + i;
    dst[(size_t)(n0 + r) * 768 + k0 + tx] = f2bf(t[tx][r]);
  }
}

// ---------------- bf16 MFMA GEMM ----------------
// out[m][n] = (A[m][:] . Wt[n][:]) + bias, 128x128 tile, BK=32, 4 waves.
// ROWBIAS=false: bias indexed by col (segmented outputs o0/o1/o2 every 768 cols).
// ROWBIAS=true : bias indexed by row, single output (used to produce V^T).
template <typename OutT, bool ROWBIAS>
__global__ __launch_bounds__(256) void gemm_mfma_kernel(
    const u16* __restrict__ A,    // [Mrows][768] bf16
    const u16* __restrict__ Wt,   // [Ncols][768] bf16
    const float* __restrict__ b0, const float* __restrict__ b1,
    OutT* __restrict__ o0, OutT* __restrict__ o1,
    int ldOut, float sc0, float sc1) {
  __shared__ u16 As[128 * 32];
  __shared__ u16 Bs[128 * 32];
  const int tid = threadIdx.x;
  const int w = tid >> 6, l = tid & 63;
  const int g = l >> 4, c = l & 15;
  const int m0 = blockIdx.y * 128;
  const int n0g = blockIdx.x * 128;
  const int seg = (!ROWBIAS && n0g >= 768) ? 1 : 0;
  const int n0 = n0g - seg * 768;
  const float* bias = (seg == 0) ? b0 : b1;
  OutT* out = (seg == 0) ? o0 : o1;
  const float sc = (seg == 0) ? sc0 : sc1;
  const int wr = (w >> 1) * 64, wc = (w & 1) * 64;

  f32x4 acc[4][4];
#pragma unroll
  for (int i = 0; i < 4; i++)
#pragma unroll
    for (int j = 0; j < 4; j++) acc[i][j] = f32x4{0.f, 0.f, 0.f, 0.f};

  for (int k0 = 0; k0 < 768; k0 += 32) {
    __syncthreads();
#pragma unroll
    for (int t = 0; t < 2; t++) {
      int ii = w * 2 + t;
      int e16 = ii * 64 + l;
      int row = e16 >> 2, slot = e16 & 3;
      int gs = slot ^ swzA(row);
      gload16(A + (size_t)(m0 + row) * 768 + k0 + gs * 8, (char*)As + ii * 1024);
    }
#pragma unroll
    for (int t = 0; t < 2; t++) {
      int ii = w * 2 + t;
      int e16 = ii * 64 + l;
      int row = e16 >> 2, slot = e16 & 3;
      int gs = slot ^ swzA(row);
      gload16(Wt + (size_t)(n0g + row) * 768 + k0 + gs * 8, (char*)Bs + ii * 1024);
    }
    __syncthreads();

    bf16x8 af[4], bfr[4];
#pragma unroll
    for (int i = 0; i < 4; i++) {
      int row = wr + i * 16 + c;
      int slot = g ^ swzA(row);
      af[i] = *(const bf16x8*)(As + row * 32 + slot * 8);
    }
#pragma unroll
    for (int j = 0; j < 4; j++) {
      int row = wc + j * 16 + c;
      int slot = g ^ swzA(row);
      bfr[j] = *(const bf16x8*)(Bs + row * 32 + slot * 8);
    }
#pragma unroll
    for (int i = 0; i < 4; i++)
#pragma unroll
      for (int j = 0; j < 4; j++)
        acc[i][j] = __builtin_amdgcn_mfma_f32_16x16x32_bf16(af[i], bfr[j], acc[i][j], 0, 0, 0);
  }

  // epilogue (C layout: col = lane&15, row = (lane>>4)*4 + reg)
  float brow[4][4];
  if (ROWBIAS) {
#pragma unroll
    for (int i = 0; i < 4; i++)
#pragma unroll
      for (int r = 0; r < 4; r++)
        brow[i][r] = b0[m0 + wr + i * 16 + g * 4 + r];
  }
#pragma unroll
  for (int j = 0; j < 4; j++) {
    int col = n0 + wc + j * 16 + c;
    float bcol = ROWBIAS ? 0.f : bias[col];
#pragma unroll
    for (int i = 0; i < 4; i++) {
#pragma unroll
      for (int r = 0; r < 4; r++) {
        int row = m0 + wr + i * 16 + g * 4 + r;
        float v = (acc[i][j][r] + (ROWBIAS ? brow[i][r] : bcol)) * sc;
        if constexpr (sizeof(OutT) == 2) {
          ((u16*)out)[(size_t)row * ldOut + col] = f2bf(v);
        } else {
          ((float*)out)[(size_t)row * ldOut + col] = v;
        }
      }
    }
  }
}

// ---------------- bf16 MFMA flash attention (causal), exp2 domain ----------------
// Block: one (b,h), 64 Q rows; 4 waves x 16 rows. KV tiles of 128.
// K staged [kv][64] (slot^row&7 swizzle); V^T staged [d][128] (slot^row&15 swizzle).
__global__ __launch_bounds__(256) void attn_mfma_kernel(
    const u16* __restrict__ Qb, const u16* __restrict__ Kb,
    const u16* __restrict__ VT, u16* __restrict__ Ob) {
  __shared__ u16 Ks[128 * 64];     // [kv][d]
  __shared__ u16 Vs[64 * 128];     // [d][kv] (V^T tile)
  __shared__ u16 Ps[4][16][132];   // per-wave P [qrow][kv], pad 132

  const int tid = threadIdx.x;
  const int w = tid >> 6, l = tid & 63;
  const int g = l >> 4, c = l & 15;

  // XCD-chunked, work-descending launch order (1536 blocks, 192 per XCD)
  const int wg = blockIdx.x;
  const int logical = (wg & 7) * 192 + (wg >> 3);
  const int bh = logical >> 4;
  const int qi = 15 - (logical & 15);
  const int q0 = qi * 64;
  const int b = bh / H, h = bh % H;
  const int qw = q0 + w * 16;

  bf16x8 qf[2];
  {
    size_t base = (size_t)(b * T + qw + c) * C + h * D;
    qf[0] = *(const bf16x8*)(Qb + base + g * 8);
    qf[1] = *(const bf16x8*)(Qb + base + 32 + g * 8);
  }

  f32x4 acc[4];
#pragma unroll
  for (int j = 0; j < 4; j++) acc[j] = f32x4{0.f, 0.f, 0.f, 0.f};
  float m_i[4], l_p[4];  // running max (log2 domain), per-lane partial l
#pragma unroll
  for (int r = 0; r < 4; r++) { m_i[r] = -1e30f; l_p[r] = 0.f; }

  const int nt = q0 / 128 + 1;
  for (int it = 0; it < nt; it++) {
    const int s0 = it * 128;
    __syncthreads();
    // stage K: 1024 16B-chunks, rows 128B / 8 slots, source pre-swizzled
#pragma unroll
    for (int t = 0; t < 4; t++) {
      int ii = w * 4 + t;
      int e16 = ii * 64 + l;
      int row = e16 >> 3, slot = e16 & 7;
      int gs = slot ^ (row & 7);
      gload16(Kb + (size_t)(b * T + s0 + row) * C + h * D + gs * 8, (char*)Ks + ii * 1024);
    }
    // stage V^T: 1024 16B-chunks, rows 256B / 16 slots, source pre-swizzled
#pragma unroll
    for (int t = 0; t < 4; t++) {
      int ii = w * 4 + t;
      int e16 = ii * 64 + l;
      int row = e16 >> 4, slot = e16 & 15;
      int gs = slot ^ (row & 15);
      gload16(VT + (size_t)(h * D + row) * M + b * T + s0 + gs * 8, (char*)Vs + ii * 1024);
    }
    __syncthreads();

    const bool active = (s0 <= qw + 15);
    if (active) {
      // S = Q' @ K^T : 8 kv-fragments of 16
      f32x4 s[8];
#pragma unroll
      for (int f = 0; f < 8; f++) s[f] = f32x4{0.f, 0.f, 0.f, 0.f};
#pragma unroll
      for (int f = 0; f < 8; f++) {
        int kvrow = f * 16 + c;
#pragma unroll
        for (int kc = 0; kc < 2; kc++) {
          int slot = (kc * 4 + g) ^ (kvrow & 7);
          bf16x8 kf = *(const bf16x8*)(Ks + kvrow * 64 + slot * 8);
          s[f] = __builtin_amdgcn_mfma_f32_16x16x32_bf16(qf[kc], kf, s[f], 0, 0, 0);
        }
      }
      // causal mask only on partial tiles (wave-uniform)
      const bool partial = (s0 + 127 > qw);
      if (partial) {
#pragma unroll
        for (int r = 0; r < 4; r++) {
          int q = qw + g * 4 + r;
#pragma unroll
          for (int f = 0; f < 8; f++) {
            int kv = s0 + f * 16 + c;
            if (kv > q) s[f][r] = -1e30f;
          }
        }
      }
      // per-row max (log2 domain)
      float mx[4];
#pragma unroll
      for (int r = 0; r < 4; r++) {
        float mr = s[0][r];
#pragma unroll
        for (int f = 1; f < 8; f++) mr = fmaxf(mr, s[f][r]);
        mx[r] = mr;
      }
#pragma unroll
      for (int off = 1; off < 16; off <<= 1)
#pragma unroll
        for (int r = 0; r < 4; r++) mx[r] = fmaxf(mx[r], __shfl_xor(mx[r], off, 64));
      // defer-max: skip rescale when max grew by <= 8 (P bounded by 2^8)
      bool defer = true;
#pragma unroll
      for (int r = 0; r < 4; r++) defer = defer && (mx[r] <= m_i[r] + 8.0f);
      if (!__all(defer)) {
#pragma unroll
        for (int r = 0; r < 4; r++) {
          float mn = fmaxf(m_i[r], mx[r]);
          float rc = exp2f(m_i[r] - mn);
          m_i[r] = mn;
          l_p[r] *= rc;
#pragma unroll
          for (int j = 0; j < 4; j++) acc[j][r] *= rc;
        }
      }
      // P = exp2(S - m), per-lane partial row sum; packed bf16 convert
#pragma unroll
      for (int r = 0; r < 4; r++) {
        float sum = 0.f;
#pragma unroll
        for (int f = 0; f < 8; f++) {
          float p = exp2f(s[f][r] - m_i[r]);
          s[f][r] = p;
          sum += p;
        }
        l_p[r] += sum;
#pragma unroll
        for (int f = 0; f < 8; f += 2) {
          __hip_bfloat162 h2 = __float22bfloat162_rn(make_float2(s[f][r], s[f + 1][r]));
          u32 pk = *(u32*)&h2;
          Ps[w][g * 4 + r][f * 16 + c] = (u16)pk;
          Ps[w][g * 4 + r][(f + 1) * 16 + c] = (u16)(pk >> 16);
        }
      }
      // O += P @ V
#pragma unroll
      for (int kc = 0; kc < 4; kc++) {
        bf16x8 pf = *(const bf16x8*)(&Ps[w][c][kc * 32 + g * 8]);
#pragma unroll
        for (int j = 0; j < 4; j++) {
          bf16x8 vf = *(const bf16x8*)(Vs + (j * 16 + c) * 128 + (((kc * 4 + g) ^ c) * 8));
          acc[j] = __builtin_amdgcn_mfma_f32_16x16x32_bf16(pf, vf, acc[j], 0, 0, 0);
        }
      }
    }
  }

  // epilogue: reduce l across the 16-lane group, normalize, store bf16
  float inv[4];
#pragma unroll
  for (int r = 0; r < 4; r++) {
    float v = l_p[r];
#pragma unroll
    for (int off = 1; off < 16; off <<= 1) v += __shfl_xor(v, off, 64);
    inv[r] = 1.f / v;
  }
#pragma unroll
  for (int j = 0; j < 4; j++) {
#pragma unroll
    for (int r = 0; r < 4; r++) {
      int row = qw + g * 4 + r;
      int col = j * 16 + c;
      Ob[(size_t)(b * T + row) * C + h * D + col] = f2bf(acc[j][r] * inv[r]);
    }
  }
}

extern "C" void kernel_launch(void* const* d_in, const int* in_sizes, int n_in,
                              void* d_out, int out_size, void* d_ws, size_t ws_size,
                              hipStream_t stream) {
  const float* x  = (const float*)d_in[0];
  const float* Wq = (const float*)d_in[2];
  const float* bq = (const float*)d_in[3];
  const float* Wk = (const float*)d_in[4];
  const float* bk = (const float*)d_in[5];
  const float* Wv = (const float*)d_in[6];
  const float* bv = (const float*)d_in[7];
  const float* Wo = (const float*)d_in[8];
  const float* bo = (const float*)d_in[9];
  float* out = (float*)d_out;

  const size_t MC2 = (size_t)M * C * 2;  // bf16 activation bytes = 12.58 MB
  char* ws = (char*)d_ws;
  u16* xb    = (u16*)(ws);
  u16* WtQKV = (u16*)(ws + MC2);
  u16* WoT   = (u16*)(ws + MC2 + 3538944);
  u16* Qb    = (u16*)(ws + MC2 + 3538944 + 1179648);
  u16* Kb    = (u16*)((char*)Qb + MC2);
  u16* VT    = (u16*)((char*)Kb + MC2);   // [768 ch][8192 tok] = V^T
  u16* Ob    = (u16*)((char*)VT + MC2);
  u16* WvT   = WtQKV + 2 * 768 * 768;

  // Q pre-scale: (1/sqrt(D)) * log2(e) -> softmax in exp2 domain
  const float qscale = 0.125f * 1.4426950408889634f;

  xconv_kernel<<<2048, 256, 0, stream>>>(x, xb, M * C / 4);
  wtrans_kernel<<<dim3(24, 24, 4), 256, 0, stream>>>(Wq, Wk, Wv, Wo, WtQKV, WoT);
  // fused QK GEMM: cols 0..767 -> Q (scaled), 768..1535 -> K
  gemm_mfma_kernel<u16, false><<<dim3(12, 64), 256, 0, stream>>>(
      xb, WtQKV, bq, bk, Qb, Kb, 768, qscale, 1.f);
  // V^T GEMM: out[n][m] = Wv^T[n][:] . x[m][:] + bv[n]  (row bias)
  gemm_mfma_kernel<u16, true><<<dim3(64, 6), 256, 0, stream>>>(
      WvT, xb, bv, bv, VT, VT, M, 1.f, 1.f);
  attn_mfma_kernel<<<1536, 256, 0, stream>>>(Qb, Kb, VT, Ob);
  gemm_mfma_kernel<float, false><<<dim3(6, 64), 256, 0, stream>>>(
      Ob, WoT, bo, bo, out, out, 768, 1.f, 1.f);
}